// Round 7
// baseline (317.300 us; speedup 1.0000x reference)
//
#include <hip/hip_runtime.h>

#define THREADS 256

typedef _Float16 f16;
typedef f16   f16x8 __attribute__((ext_vector_type(8)));
typedef float f32x4 __attribute__((ext_vector_type(4)));

__global__ void k_zero_cnt(unsigned* __restrict__ cnt, int n){
  int i = blockIdx.x*blockDim.x + threadIdx.x;
  if(i < n) cnt[i] = 0u;
}

__global__ void k_count(const int* __restrict__ dst, unsigned* __restrict__ cnt, int E){
  int e = blockIdx.x*blockDim.x + threadIdx.x;
  if(e < E) atomicAdd(&cnt[dst[e]], 1u);
}

// ---- hierarchical exclusive scan over cnt[0..M) ----
__global__ void k_scan_local(const unsigned* __restrict__ cnt, int* __restrict__ off,
                             int* __restrict__ partials, int M){
  __shared__ int ts[256];
  const int t = threadIdx.x;
  const int base = blockIdx.x*1024 + t*4;
  int4 v = make_int4(0,0,0,0);
  if(base+3 < M) v = *(const int4*)(cnt+base);
  else {
    if(base+0<M) v.x=(int)cnt[base+0];
    if(base+1<M) v.y=(int)cnt[base+1];
    if(base+2<M) v.z=(int)cnt[base+2];
  }
  ts[t] = v.x+v.y+v.z+v.w;
  __syncthreads();
  for(int o=1;o<256;o<<=1){
    int u = (t>=o)? ts[t-o] : 0;
    __syncthreads();
    ts[t] += u;
    __syncthreads();
  }
  int ex = (t==0)? 0 : ts[t-1];
  if(base+0<M) off[base+0] = ex;
  if(base+1<M) off[base+1] = ex + v.x;
  if(base+2<M) off[base+2] = ex + v.x + v.y;
  if(base+3<M) off[base+3] = ex + v.x + v.y + v.z;
  if(t==255) partials[blockIdx.x] = ts[255];
}

__global__ void k_scan_part(int* __restrict__ partials, int NB){
  const int t = threadIdx.x;   // 64 threads
  int v = (t<NB)? partials[t] : 0;
  int s = v;
  for(int o=1;o<64;o<<=1){
    int u = __shfl_up(s, o);
    if(t >= o) s += u;
  }
  if(t<NB) partials[t] = s - v;
}

__global__ void k_scan_add(const unsigned* __restrict__ cnt, int* __restrict__ off,
                           const int* __restrict__ partials, float* __restrict__ dinv,
                           int* __restrict__ cursor, int M, int E){
  int i = blockIdx.x*blockDim.x + threadIdx.x;
  if(i < M){
    int o = off[i] + partials[i>>10];
    off[i] = o;
    cursor[i] = o;
    dinv[i] = rsqrtf((float)(cnt[i] + 1u));  // +1 self-loop
  }
  if(i == 0) off[M] = E;
}

__global__ void k_build(const int* __restrict__ ei, int* __restrict__ cursor,
                        int* __restrict__ ssrc, int E){
  int e = blockIdx.x*blockDim.x + threadIdx.x;
  if(e < E){
    int s = ei[e], d = ei[E+e];
    int p = atomicAdd(&cursor[d], 1);
    ssrc[p] = s;
  }
}

// ---- MFMA GEMM with f16x2 error-compensated split ----
template<int K, int N, bool RELU>
__global__ void k_gemm_mfma(const float* __restrict__ A, const float* __restrict__ W,
                            const float* __restrict__ dinv, float* __restrict__ H, int M){
  constexpr int BM = 128, BK = 32, BN = N;
  constexpr int AST = 40;                 // padded k stride (halfs)
  constexpr int NM = 4;
  constexpr int NN = BN/32;
  constexpr int SKN = BK*BN/THREADS;
  __shared__ f16 Ah[BM*AST], Al[BM*AST], Bh[BN*AST], Bl[BN*AST];

  const int tid  = threadIdx.x;
  const int row0 = blockIdx.x*BM;
  const int wv = tid>>6, l = tid&63;
  const int wr = wv>>1, wc = wv&1;
  const int lr = l&15, lk = l>>4;

  const int sar = tid>>1, sak = (tid&1)*16;
  const long long garow = min(row0+sar, M-1);
  const int sc = tid % BN, sk0 = (tid/BN)*SKN;

  f32x4 acc[NM][NN] = {};

  for(int k0 = 0; k0 < K; k0 += BK){
    float avals[16];
    #pragma unroll
    for(int q=0;q<4;q++){
      float4 v = *(const float4*)(A + garow*K + k0 + sak + q*4);
      if(RELU){
        v.x=fmaxf(v.x,0.f); v.y=fmaxf(v.y,0.f);
        v.z=fmaxf(v.z,0.f); v.w=fmaxf(v.w,0.f);
      }
      avals[q*4+0]=v.x; avals[q*4+1]=v.y; avals[q*4+2]=v.z; avals[q*4+3]=v.w;
    }
    float bvals[SKN];
    #pragma unroll
    for(int i=0;i<SKN;i++) bvals[i] = W[(size_t)(k0+sk0+i)*N + sc];

    __syncthreads();

    #pragma unroll
    for(int s=0;s<2;s++){
      f16x8 hi, lo;
      #pragma unroll
      for(int j=0;j<8;j++){
        float x = avals[s*8+j];
        f16 h = (f16)x;
        hi[j] = h; lo[j] = (f16)(x - (float)h);
      }
      *(f16x8*)&Ah[sar*AST + sak + s*8] = hi;
      *(f16x8*)&Al[sar*AST + sak + s*8] = lo;
    }
    #pragma unroll
    for(int s=0;s<SKN/8;s++){
      f16x8 hi, lo;
      #pragma unroll
      for(int j=0;j<8;j++){
        float x = bvals[s*8+j];
        f16 h = (f16)x;
        hi[j] = h; lo[j] = (f16)(x - (float)h);
      }
      *(f16x8*)&Bh[sc*AST + sk0 + s*8] = hi;
      *(f16x8*)&Bl[sc*AST + sk0 + s*8] = lo;
    }
    __syncthreads();

    f16x8 afh[NM], afl[NM], bfh[NN], bfl[NN];
    #pragma unroll
    for(int m=0;m<NM;m++){
      int r = wr*64 + m*16 + lr;
      afh[m] = *(const f16x8*)&Ah[r*AST + lk*8];
      afl[m] = *(const f16x8*)&Al[r*AST + lk*8];
    }
    #pragma unroll
    for(int n=0;n<NN;n++){
      int c = wc*(BN/2) + n*16 + lr;
      bfh[n] = *(const f16x8*)&Bh[c*AST + lk*8];
      bfl[n] = *(const f16x8*)&Bl[c*AST + lk*8];
    }
    #pragma unroll
    for(int m=0;m<NM;m++)
      #pragma unroll
      for(int n=0;n<NN;n++){
        acc[m][n] = __builtin_amdgcn_mfma_f32_16x16x32_f16(afh[m], bfh[n], acc[m][n], 0,0,0);
        acc[m][n] = __builtin_amdgcn_mfma_f32_16x16x32_f16(afh[m], bfl[n], acc[m][n], 0,0,0);
        acc[m][n] = __builtin_amdgcn_mfma_f32_16x16x32_f16(afl[m], bfh[n], acc[m][n], 0,0,0);
      }
  }

  #pragma unroll
  for(int m=0;m<NM;m++){
    int grb = row0 + wr*64 + m*16 + lk*4;
    #pragma unroll
    for(int reg=0;reg<4;reg++){
      int gr = grb + reg;
      if(gr < M){
        float dv = dinv[gr];
        #pragma unroll
        for(int n=0;n<NN;n++){
          int gc = wc*(BN/2) + n*16 + lr;
          H[(size_t)gr*N + gc] = acc[m][n][reg] * dv;
        }
      }
    }
  }
}

// ---- column-partitioned gather ----
// Grid: NG col-groups x node-blocks, blockIdx.x % NG = col-group.
// With round-robin block->XCD dispatch, each XCD touches only a 16-col slice
// of g (50000*64B = 3.2MB < 4MB L2) -> gathers hit in-XCD L2.
// 16-lane group per node: lane reads g[row*NC + cg*16 + (lane&15)] per edge.
template<int NC, int NG>
__global__ void k_gather2(const int* __restrict__ off, const int* __restrict__ ssrc,
                          const float* __restrict__ g, const float* __restrict__ dinv,
                          const float* __restrict__ bias, float* __restrict__ out, int M){
  const int cg   = blockIdx.x % NG;
  const int nb   = blockIdx.x / NG;
  const int tid  = threadIdx.x;
  const int wave = tid >> 6;
  const int lane = tid & 63;
  const int sub  = lane >> 4;          // node within wave (0..3)
  const int c    = lane & 15;          // column within group
  const int w    = nb*16 + wave*4 + sub;
  if(w >= M) return;
  const int col = cg*16 + c;
  const float* gc = g + col;
  float acc = gc[(size_t)w*NC];        // self-loop term
  const int e0 = off[w], e1 = off[w+1];
  int i = e0;
  for(; i+1 < e1; i += 2){
    int s0 = ssrc[i], s1 = ssrc[i+1];
    acc += gc[(size_t)s0*NC] + gc[(size_t)s1*NC];
  }
  if(i < e1) acc += gc[(size_t)ssrc[i]*NC];
  out[(size_t)w*NC + col] = fmaf(acc, dinv[w], bias[col]);
}

extern "C" void kernel_launch(void* const* d_in, const int* in_sizes, int n_in,
                              void* d_out, int out_size, void* d_ws, size_t ws_size,
                              hipStream_t stream){
  const float* feat = (const float*)d_in[0];
  const int*   ei   = (const int*)d_in[1];
  const float* W1   = (const float*)d_in[2];
  const float* b1   = (const float*)d_in[3];
  const float* W2   = (const float*)d_in[4];
  const float* b2   = (const float*)d_in[5];
  float* out = (float*)d_out;

  const int M = in_sizes[0] / 256;   // 50000 nodes
  const int E = in_sizes[1] / 2;     // 800000 edges

  float* ws = (float*)d_ws;
  unsigned* cnt  = (unsigned*)ws;             // [0, 50176)
  float*    dinv = ws + 50176;                // [50176, 100352)
  int*      off  = (int*)(ws + 100352);       // 50001 ints
  int*      curs = (int*)(ws + 150656);       // 50176 ints
  int*      part = (int*)(ws + 200832);       // 64 ints
  int*      ssrc = (int*)(ws + 200960);       // 800000 ints
  float*    h1   = ws + 1000960;              // M*128
  float*    out1 = h1 + (size_t)M*128;        // M*128
  float*    h2   = h1;                        // reuse (dead after gather1)

  const int nbN = (M + THREADS-1)/THREADS;
  const int nbE = (E + THREADS-1)/THREADS;
  const int nbScan = (M + 1023)/1024;         // 49

  // CSR build (dst-sorted)
  k_zero_cnt<<<nbN, THREADS, 0, stream>>>(cnt, M);
  k_count<<<nbE, THREADS, 0, stream>>>(ei + E, cnt, E);
  k_scan_local<<<nbScan, 256, 0, stream>>>(cnt, off, part, M);
  k_scan_part<<<1, 64, 0, stream>>>(part, nbScan);
  k_scan_add<<<nbN, THREADS, 0, stream>>>(cnt, off, part, dinv, curs, M, E);
  k_build<<<nbE, THREADS, 0, stream>>>(ei, curs, ssrc, E);

  const int nodeBlocks = (M + 15)/16;
  const int gemmBlocks = (M + 127)/128;

  // ----- layer 1: 256 -> 128 -----
  k_gemm_mfma<256,128,false><<<gemmBlocks, THREADS, 0, stream>>>(feat, W1, dinv, h1, M);
  k_gather2<128,8><<<nodeBlocks*8, THREADS, 0, stream>>>(off, ssrc, h1, dinv, b1, out1, M);

  // ----- layer 2: 128 -> 64 (relu fused into A staging) -----
  k_gemm_mfma<128,64,true><<<gemmBlocks, THREADS, 0, stream>>>(out1, W2, dinv, h2, M);
  k_gather2<64,4><<<nodeBlocks*4, THREADS, 0, stream>>>(off, ssrc, h2, dinv, b2, out, M);
}

// Round 8
// 225.113 us; speedup vs baseline: 1.4095x; 1.4095x over previous
//
#include <hip/hip_runtime.h>

#define THREADS 256

typedef _Float16 f16;
typedef f16   f16x2 __attribute__((ext_vector_type(2)));
typedef f16   f16x8 __attribute__((ext_vector_type(8)));
typedef float f32x4 __attribute__((ext_vector_type(4)));

__global__ void k_zero_cnt(unsigned* __restrict__ cnt, int n){
  int i = blockIdx.x*blockDim.x + threadIdx.x;
  if(i < n) cnt[i] = 0u;
}

__global__ void k_count(const int* __restrict__ dst, unsigned* __restrict__ cnt, int E){
  int e = blockIdx.x*blockDim.x + threadIdx.x;
  if(e < E) atomicAdd(&cnt[dst[e]], 1u);
}

// ---- hierarchical exclusive scan over cnt[0..M) ----
__global__ void k_scan_local(const unsigned* __restrict__ cnt, int* __restrict__ off,
                             int* __restrict__ partials, int M){
  __shared__ int ts[256];
  const int t = threadIdx.x;
  const int base = blockIdx.x*1024 + t*4;
  int4 v = make_int4(0,0,0,0);
  if(base+3 < M) v = *(const int4*)(cnt+base);
  else {
    if(base+0<M) v.x=(int)cnt[base+0];
    if(base+1<M) v.y=(int)cnt[base+1];
    if(base+2<M) v.z=(int)cnt[base+2];
  }
  ts[t] = v.x+v.y+v.z+v.w;
  __syncthreads();
  for(int o=1;o<256;o<<=1){
    int u = (t>=o)? ts[t-o] : 0;
    __syncthreads();
    ts[t] += u;
    __syncthreads();
  }
  int ex = (t==0)? 0 : ts[t-1];
  if(base+0<M) off[base+0] = ex;
  if(base+1<M) off[base+1] = ex + v.x;
  if(base+2<M) off[base+2] = ex + v.x + v.y;
  if(base+3<M) off[base+3] = ex + v.x + v.y + v.z;
  if(t==255) partials[blockIdx.x] = ts[255];
}

__global__ void k_scan_part(int* __restrict__ partials, int NB){
  const int t = threadIdx.x;   // 64 threads
  int v = (t<NB)? partials[t] : 0;
  int s = v;
  for(int o=1;o<64;o<<=1){
    int u = __shfl_up(s, o);
    if(t >= o) s += u;
  }
  if(t<NB) partials[t] = s - v;
}

__global__ void k_scan_add(const unsigned* __restrict__ cnt, int* __restrict__ off,
                           const int* __restrict__ partials, float* __restrict__ dinv,
                           int* __restrict__ cursor, int M, int E){
  int i = blockIdx.x*blockDim.x + threadIdx.x;
  if(i < M){
    int o = off[i] + partials[i>>10];
    off[i] = o;
    cursor[i] = o;
    dinv[i] = rsqrtf((float)(cnt[i] + 1u));  // +1 self-loop
  }
  if(i == 0) off[M] = E;
}

__global__ void k_build(const int* __restrict__ ei, int* __restrict__ cursor,
                        int* __restrict__ ssrc, int E){
  int e = blockIdx.x*blockDim.x + threadIdx.x;
  if(e < E){
    int s = ei[e], d = ei[E+e];
    int p = atomicAdd(&cursor[d], 1);
    ssrc[p] = s;
  }
}

// ---- MFMA GEMM, f32 A (hi/lo split both operands), f16 output ----
// Hh[M,N] = (A[M,K] @ W[K,N]) * dinv[row], rounded to f16.
template<int K, int N>
__global__ void k_gemm_mfma_f32(const float* __restrict__ A, const float* __restrict__ W,
                                const float* __restrict__ dinv, f16* __restrict__ Hh, int M){
  constexpr int BM = 128, BK = 32, BN = N;
  constexpr int AST = 40;
  constexpr int NM = 4;
  constexpr int NN = BN/32;
  constexpr int SKN = BK*BN/THREADS;
  __shared__ f16 Ah[BM*AST], Al[BM*AST], Bh[BN*AST], Bl[BN*AST];

  const int tid  = threadIdx.x;
  const int row0 = blockIdx.x*BM;
  const int wv = tid>>6, l = tid&63;
  const int wr = wv>>1, wc = wv&1;
  const int lr = l&15, lk = l>>4;

  const int sar = tid>>1, sak = (tid&1)*16;
  const long long garow = min(row0+sar, M-1);
  const int sc = tid % BN, sk0 = (tid/BN)*SKN;

  f32x4 acc[NM][NN] = {};

  for(int k0 = 0; k0 < K; k0 += BK){
    float avals[16];
    #pragma unroll
    for(int q=0;q<4;q++){
      float4 v = *(const float4*)(A + garow*K + k0 + sak + q*4);
      avals[q*4+0]=v.x; avals[q*4+1]=v.y; avals[q*4+2]=v.z; avals[q*4+3]=v.w;
    }
    float bvals[SKN];
    #pragma unroll
    for(int i=0;i<SKN;i++) bvals[i] = W[(size_t)(k0+sk0+i)*N + sc];

    __syncthreads();

    #pragma unroll
    for(int s=0;s<2;s++){
      f16x8 hi, lo;
      #pragma unroll
      for(int j=0;j<8;j++){
        float x = avals[s*8+j];
        f16 h = (f16)x;
        hi[j] = h; lo[j] = (f16)(x - (float)h);
      }
      *(f16x8*)&Ah[sar*AST + sak + s*8] = hi;
      *(f16x8*)&Al[sar*AST + sak + s*8] = lo;
    }
    #pragma unroll
    for(int s=0;s<SKN/8;s++){
      f16x8 hi, lo;
      #pragma unroll
      for(int j=0;j<8;j++){
        float x = bvals[s*8+j];
        f16 h = (f16)x;
        hi[j] = h; lo[j] = (f16)(x - (float)h);
      }
      *(f16x8*)&Bh[sc*AST + sk0 + s*8] = hi;
      *(f16x8*)&Bl[sc*AST + sk0 + s*8] = lo;
    }
    __syncthreads();

    f16x8 afh[NM], afl[NM], bfh[NN], bfl[NN];
    #pragma unroll
    for(int m=0;m<NM;m++){
      int r = wr*64 + m*16 + lr;
      afh[m] = *(const f16x8*)&Ah[r*AST + lk*8];
      afl[m] = *(const f16x8*)&Al[r*AST + lk*8];
    }
    #pragma unroll
    for(int n=0;n<NN;n++){
      int c = wc*(BN/2) + n*16 + lr;
      bfh[n] = *(const f16x8*)&Bh[c*AST + lk*8];
      bfl[n] = *(const f16x8*)&Bl[c*AST + lk*8];
    }
    #pragma unroll
    for(int m=0;m<NM;m++)
      #pragma unroll
      for(int n=0;n<NN;n++){
        acc[m][n] = __builtin_amdgcn_mfma_f32_16x16x32_f16(afh[m], bfh[n], acc[m][n], 0,0,0);
        acc[m][n] = __builtin_amdgcn_mfma_f32_16x16x32_f16(afh[m], bfl[n], acc[m][n], 0,0,0);
        acc[m][n] = __builtin_amdgcn_mfma_f32_16x16x32_f16(afl[m], bfh[n], acc[m][n], 0,0,0);
      }
  }

  #pragma unroll
  for(int m=0;m<NM;m++){
    int grb = row0 + wr*64 + m*16 + lk*4;
    #pragma unroll
    for(int reg=0;reg<4;reg++){
      int gr = grb + reg;
      if(gr < M){
        float dv = dinv[gr];
        #pragma unroll
        for(int n=0;n<NN;n++){
          int gc = wc*(BN/2) + n*16 + lr;
          Hh[(size_t)gr*N + gc] = (f16)(acc[m][n][reg] * dv);
        }
      }
    }
  }
}

// ---- MFMA GEMM, f16 A (no A split), f32 W hi/lo split, f16 output ----
template<int K, int N>
__global__ void k_gemm_mfma_f16a(const f16* __restrict__ A, const float* __restrict__ W,
                                 const float* __restrict__ dinv, f16* __restrict__ Hh, int M){
  constexpr int BM = 128, BK = 32, BN = N;
  constexpr int AST = 40;
  constexpr int NM = 4;
  constexpr int NN = BN/32;               // 2 for BN=64
  constexpr int SKN = BK*BN/THREADS;      // 8
  __shared__ f16 Ah[BM*AST], Bh[BN*AST], Bl[BN*AST];

  const int tid  = threadIdx.x;
  const int row0 = blockIdx.x*BM;
  const int wv = tid>>6, l = tid&63;
  const int wr = wv>>1, wc = wv&1;
  const int lr = l&15, lk = l>>4;

  const int sar = tid>>1, sak = (tid&1)*16;
  const long long garow = min(row0+sar, M-1);
  const int sc = tid % BN, sk0 = (tid/BN)*SKN;

  f32x4 acc[NM][NN] = {};

  for(int k0 = 0; k0 < K; k0 += BK){
    f16x8 av[2];
    av[0] = *(const f16x8*)(A + garow*K + k0 + sak);
    av[1] = *(const f16x8*)(A + garow*K + k0 + sak + 8);
    float bvals[SKN];
    #pragma unroll
    for(int i=0;i<SKN;i++) bvals[i] = W[(size_t)(k0+sk0+i)*N + sc];

    __syncthreads();

    *(f16x8*)&Ah[sar*AST + sak]     = av[0];
    *(f16x8*)&Ah[sar*AST + sak + 8] = av[1];
    #pragma unroll
    for(int s=0;s<SKN/8;s++){
      f16x8 hi, lo;
      #pragma unroll
      for(int j=0;j<8;j++){
        float x = bvals[s*8+j];
        f16 h = (f16)x;
        hi[j] = h; lo[j] = (f16)(x - (float)h);
      }
      *(f16x8*)&Bh[sc*AST + sk0 + s*8] = hi;
      *(f16x8*)&Bl[sc*AST + sk0 + s*8] = lo;
    }
    __syncthreads();

    f16x8 af[NM], bfh[NN], bfl[NN];
    #pragma unroll
    for(int m=0;m<NM;m++){
      int r = wr*64 + m*16 + lr;
      af[m] = *(const f16x8*)&Ah[r*AST + lk*8];
    }
    #pragma unroll
    for(int n=0;n<NN;n++){
      int c = wc*(BN/2) + n*16 + lr;
      bfh[n] = *(const f16x8*)&Bh[c*AST + lk*8];
      bfl[n] = *(const f16x8*)&Bl[c*AST + lk*8];
    }
    #pragma unroll
    for(int m=0;m<NM;m++)
      #pragma unroll
      for(int n=0;n<NN;n++){
        acc[m][n] = __builtin_amdgcn_mfma_f32_16x16x32_f16(af[m], bfh[n], acc[m][n], 0,0,0);
        acc[m][n] = __builtin_amdgcn_mfma_f32_16x16x32_f16(af[m], bfl[n], acc[m][n], 0,0,0);
      }
  }

  #pragma unroll
  for(int m=0;m<NM;m++){
    int grb = row0 + wr*64 + m*16 + lk*4;
    #pragma unroll
    for(int reg=0;reg<4;reg++){
      int gr = grb + reg;
      if(gr < M){
        float dv = dinv[gr];
        #pragma unroll
        for(int n=0;n<NN;n++){
          int gc = wc*(BN/2) + n*16 + lr;
          Hh[(size_t)gr*N + gc] = (f16)(acc[m][n][reg] * dv);
        }
      }
    }
  }
}

// gather, NC=128, f16 in / f16 out, ReLU fused: one wave per node.
__global__ void k_gather_l1(const int* __restrict__ off, const int* __restrict__ ssrc,
                            const f16* __restrict__ g, const float* __restrict__ dinv,
                            const float* __restrict__ bias, f16* __restrict__ outh, int M){
  const int w    = (blockIdx.x * blockDim.x + threadIdx.x) >> 6;
  const int lane = threadIdx.x & 63;
  if(w >= M) return;
  const f16x2* g2 = (const f16x2*)g;
  f16x2 sv = g2[(size_t)w*64 + lane];
  float ax = (float)sv[0], ay = (float)sv[1];
  const int e0 = off[w], e1 = off[w+1];
  int i = e0;
  for(; i+1 < e1; i += 2){
    int s0 = ssrc[i], s1 = ssrc[i+1];
    f16x2 v0 = g2[(size_t)s0*64 + lane];
    f16x2 v1 = g2[(size_t)s1*64 + lane];
    ax += (float)v0[0] + (float)v1[0];
    ay += (float)v0[1] + (float)v1[1];
  }
  if(i < e1){
    f16x2 v = g2[(size_t)ssrc[i]*64 + lane];
    ax += (float)v[0]; ay += (float)v[1];
  }
  const float dd = dinv[w];
  float2 bb = ((const float2*)bias)[lane];
  float ox = fmaxf(fmaf(ax, dd, bb.x), 0.f);
  float oy = fmaxf(fmaf(ay, dd, bb.y), 0.f);
  f16x2 o; o[0] = (f16)ox; o[1] = (f16)oy;
  ((f16x2*)outh)[(size_t)w*64 + lane] = o;
}

// gather, NC=64, f16 in / f32 out (final): 32-lane half-wave per node.
__global__ void k_gather_l2(const int* __restrict__ off, const int* __restrict__ ssrc,
                            const f16* __restrict__ g, const float* __restrict__ dinv,
                            const float* __restrict__ bias, float* __restrict__ out, int M){
  const int id   = blockIdx.x * blockDim.x + threadIdx.x;
  const int w    = id >> 5;
  const int l32  = id & 31;
  if(w >= M) return;
  const f16x2* g2 = (const f16x2*)g;
  f16x2 sv = g2[(size_t)w*32 + l32];
  float ax = (float)sv[0], ay = (float)sv[1];
  const int e0 = off[w], e1 = off[w+1];
  int i = e0;
  for(; i+1 < e1; i += 2){
    int s0 = ssrc[i], s1 = ssrc[i+1];
    f16x2 v0 = g2[(size_t)s0*32 + l32];
    f16x2 v1 = g2[(size_t)s1*32 + l32];
    ax += (float)v0[0] + (float)v1[0];
    ay += (float)v0[1] + (float)v1[1];
  }
  if(i < e1){
    f16x2 v = g2[(size_t)ssrc[i]*32 + l32];
    ax += (float)v[0]; ay += (float)v[1];
  }
  const float dd = dinv[w];
  float2 bb = ((const float2*)bias)[l32];
  float2 o;
  o.x = fmaf(ax, dd, bb.x);
  o.y = fmaf(ay, dd, bb.y);
  ((float2*)out)[(size_t)w*32 + l32] = o;
}

extern "C" void kernel_launch(void* const* d_in, const int* in_sizes, int n_in,
                              void* d_out, int out_size, void* d_ws, size_t ws_size,
                              hipStream_t stream){
  const float* feat = (const float*)d_in[0];
  const int*   ei   = (const int*)d_in[1];
  const float* W1   = (const float*)d_in[2];
  const float* b1   = (const float*)d_in[3];
  const float* W2   = (const float*)d_in[4];
  const float* b2   = (const float*)d_in[5];
  float* out = (float*)d_out;

  const int M = in_sizes[0] / 256;   // 50000 nodes
  const int E = in_sizes[1] / 2;     // 800000 edges

  float* ws = (float*)d_ws;
  unsigned* cnt  = (unsigned*)ws;             // [0, 50176)
  float*    dinv = ws + 50176;                // [50176, 100352)
  int*      off  = (int*)(ws + 100352);       // 50001 ints
  int*      curs = (int*)(ws + 150656);       // 50176 ints
  int*      part = (int*)(ws + 200832);       // 64 ints
  int*      ssrc = (int*)(ws + 200960);       // 800000 ints
  f16*      h1h  = (f16*)(ws + 1000960);      // M*128 f16 (3.2M floats)
  f16*      o1h  = (f16*)(ws + 4200960);      // M*128 f16
  f16*      h2h  = h1h;                       // reuse (dead after gather1)

  const int nbN = (M + THREADS-1)/THREADS;
  const int nbE = (E + THREADS-1)/THREADS;
  const int nbScan = (M + 1023)/1024;         // 49

  // CSR build (dst-sorted)
  k_zero_cnt<<<nbN, THREADS, 0, stream>>>(cnt, M);
  k_count<<<nbE, THREADS, 0, stream>>>(ei + E, cnt, E);
  k_scan_local<<<nbScan, 256, 0, stream>>>(cnt, off, part, M);
  k_scan_part<<<1, 64, 0, stream>>>(part, nbScan);
  k_scan_add<<<nbN, THREADS, 0, stream>>>(cnt, off, part, dinv, curs, M, E);
  k_build<<<nbE, THREADS, 0, stream>>>(ei, curs, ssrc, E);

  const int gemmBlocks = (M + 127)/128;

  // ----- layer 1: 256 -> 128 -----
  k_gemm_mfma_f32<256,128><<<gemmBlocks, THREADS, 0, stream>>>(feat, W1, dinv, h1h, M);
  k_gather_l1<<<(M*64 + THREADS-1)/THREADS, THREADS, 0, stream>>>(off, ssrc, h1h, dinv, b1, o1h, M);

  // ----- layer 2: 128 -> 64 -----
  k_gemm_mfma_f16a<128,64><<<gemmBlocks, THREADS, 0, stream>>>(o1h, W2, dinv, h2h, M);
  k_gather_l2<<<(M*32 + THREADS-1)/THREADS, THREADS, 0, stream>>>(off, ssrc, h2h, dinv, b2, out, M);
}

// Round 9
// 215.434 us; speedup vs baseline: 1.4728x; 1.0449x over previous
//
#include <hip/hip_runtime.h>

#define THREADS 256

typedef _Float16 f16;
typedef f16   f16x2 __attribute__((ext_vector_type(2)));
typedef f16   f16x8 __attribute__((ext_vector_type(8)));
typedef float f32x4 __attribute__((ext_vector_type(4)));

__global__ void k_zero_cnt(unsigned* __restrict__ cnt, int n){
  int i = blockIdx.x*blockDim.x + threadIdx.x;
  if(i < n) cnt[i] = 0u;
}

__global__ void k_count(const int* __restrict__ dst, unsigned* __restrict__ cnt, int E){
  int e = blockIdx.x*blockDim.x + threadIdx.x;
  if(e < E) atomicAdd(&cnt[dst[e]], 1u);
}

// ---- hierarchical exclusive scan over cnt[0..M) ----
__global__ void k_scan_local(const unsigned* __restrict__ cnt, int* __restrict__ off,
                             int* __restrict__ partials, int M){
  __shared__ int ts[256];
  const int t = threadIdx.x;
  const int base = blockIdx.x*1024 + t*4;
  int4 v = make_int4(0,0,0,0);
  if(base+3 < M) v = *(const int4*)(cnt+base);
  else {
    if(base+0<M) v.x=(int)cnt[base+0];
    if(base+1<M) v.y=(int)cnt[base+1];
    if(base+2<M) v.z=(int)cnt[base+2];
  }
  ts[t] = v.x+v.y+v.z+v.w;
  __syncthreads();
  for(int o=1;o<256;o<<=1){
    int u = (t>=o)? ts[t-o] : 0;
    __syncthreads();
    ts[t] += u;
    __syncthreads();
  }
  int ex = (t==0)? 0 : ts[t-1];
  if(base+0<M) off[base+0] = ex;
  if(base+1<M) off[base+1] = ex + v.x;
  if(base+2<M) off[base+2] = ex + v.x + v.y;
  if(base+3<M) off[base+3] = ex + v.x + v.y + v.z;
  if(t==255) partials[blockIdx.x] = ts[255];
}

__global__ void k_scan_part(int* __restrict__ partials, int NB){
  const int t = threadIdx.x;   // 64 threads
  int v = (t<NB)? partials[t] : 0;
  int s = v;
  for(int o=1;o<64;o<<=1){
    int u = __shfl_up(s, o);
    if(t >= o) s += u;
  }
  if(t<NB) partials[t] = s - v;
}

__global__ void k_scan_add(const unsigned* __restrict__ cnt, int* __restrict__ off,
                           const int* __restrict__ partials, float* __restrict__ dinv,
                           int* __restrict__ cursor, int M, int E){
  int i = blockIdx.x*blockDim.x + threadIdx.x;
  if(i < M){
    int o = off[i] + partials[i>>10];
    off[i] = o;
    cursor[i] = o;
    dinv[i] = rsqrtf((float)(cnt[i] + 1u));  // +1 self-loop
  }
  if(i == 0) off[M] = E;
}

// dst-range-partitioned build: blockIdx&7 selects a dst range; with round-robin
// block->XCD dispatch each ssrc window (~400KB) is written by ONE XCD only ->
// no cross-XCD line ping-pong -> writeback ~= payload (3.2MB) instead of 16x.
__global__ void k_build(const int* __restrict__ ei, int* __restrict__ cursor,
                        int* __restrict__ ssrc, int E, int M){
  const int grp = blockIdx.x & 7;
  const int nb  = blockIdx.x >> 3;
  const int lo  = grp * (M >> 3);
  const int hi  = (grp == 7) ? M : lo + (M >> 3);
  int e = nb*THREADS + threadIdx.x;
  if(e < E){
    int d = ei[E+e];
    if(d >= lo && d < hi){
      int s = ei[e];
      int p = atomicAdd(&cursor[d], 1);
      ssrc[p] = s;
    }
  }
}

// ---- MFMA GEMM, f32 A (hi/lo split both operands), f16 output ----
template<int K, int N>
__global__ void k_gemm_mfma_f32(const float* __restrict__ A, const float* __restrict__ W,
                                const float* __restrict__ dinv, f16* __restrict__ Hh, int M){
  constexpr int BM = 128, BK = 32, BN = N;
  constexpr int AST = 40;
  constexpr int NM = 4;
  constexpr int NN = BN/32;
  constexpr int SKN = BK*BN/THREADS;
  __shared__ f16 Ah[BM*AST], Al[BM*AST], Bh[BN*AST], Bl[BN*AST];

  const int tid  = threadIdx.x;
  const int row0 = blockIdx.x*BM;
  const int wv = tid>>6, l = tid&63;
  const int wr = wv>>1, wc = wv&1;
  const int lr = l&15, lk = l>>4;

  const int sar = tid>>1, sak = (tid&1)*16;
  const long long garow = min(row0+sar, M-1);
  const int sc = tid % BN, sk0 = (tid/BN)*SKN;

  f32x4 acc[NM][NN] = {};

  for(int k0 = 0; k0 < K; k0 += BK){
    float avals[16];
    #pragma unroll
    for(int q=0;q<4;q++){
      float4 v = *(const float4*)(A + garow*K + k0 + sak + q*4);
      avals[q*4+0]=v.x; avals[q*4+1]=v.y; avals[q*4+2]=v.z; avals[q*4+3]=v.w;
    }
    float bvals[SKN];
    #pragma unroll
    for(int i=0;i<SKN;i++) bvals[i] = W[(size_t)(k0+sk0+i)*N + sc];

    __syncthreads();

    #pragma unroll
    for(int s=0;s<2;s++){
      f16x8 hi, lo;
      #pragma unroll
      for(int j=0;j<8;j++){
        float x = avals[s*8+j];
        f16 h = (f16)x;
        hi[j] = h; lo[j] = (f16)(x - (float)h);
      }
      *(f16x8*)&Ah[sar*AST + sak + s*8] = hi;
      *(f16x8*)&Al[sar*AST + sak + s*8] = lo;
    }
    #pragma unroll
    for(int s=0;s<SKN/8;s++){
      f16x8 hi, lo;
      #pragma unroll
      for(int j=0;j<8;j++){
        float x = bvals[s*8+j];
        f16 h = (f16)x;
        hi[j] = h; lo[j] = (f16)(x - (float)h);
      }
      *(f16x8*)&Bh[sc*AST + sk0 + s*8] = hi;
      *(f16x8*)&Bl[sc*AST + sk0 + s*8] = lo;
    }
    __syncthreads();

    f16x8 afh[NM], afl[NM], bfh[NN], bfl[NN];
    #pragma unroll
    for(int m=0;m<NM;m++){
      int r = wr*64 + m*16 + lr;
      afh[m] = *(const f16x8*)&Ah[r*AST + lk*8];
      afl[m] = *(const f16x8*)&Al[r*AST + lk*8];
    }
    #pragma unroll
    for(int n=0;n<NN;n++){
      int c = wc*(BN/2) + n*16 + lr;
      bfh[n] = *(const f16x8*)&Bh[c*AST + lk*8];
      bfl[n] = *(const f16x8*)&Bl[c*AST + lk*8];
    }
    #pragma unroll
    for(int m=0;m<NM;m++)
      #pragma unroll
      for(int n=0;n<NN;n++){
        acc[m][n] = __builtin_amdgcn_mfma_f32_16x16x32_f16(afh[m], bfh[n], acc[m][n], 0,0,0);
        acc[m][n] = __builtin_amdgcn_mfma_f32_16x16x32_f16(afh[m], bfl[n], acc[m][n], 0,0,0);
        acc[m][n] = __builtin_amdgcn_mfma_f32_16x16x32_f16(afl[m], bfh[n], acc[m][n], 0,0,0);
      }
  }

  #pragma unroll
  for(int m=0;m<NM;m++){
    int grb = row0 + wr*64 + m*16 + lk*4;
    #pragma unroll
    for(int reg=0;reg<4;reg++){
      int gr = grb + reg;
      if(gr < M){
        float dv = dinv[gr];
        #pragma unroll
        for(int n=0;n<NN;n++){
          int gc = wc*(BN/2) + n*16 + lr;
          Hh[(size_t)gr*N + gc] = (f16)(acc[m][n][reg] * dv);
        }
      }
    }
  }
}

// ---- MFMA GEMM, f16 A (no A split), f32 W hi/lo split, f16 output ----
template<int K, int N>
__global__ void k_gemm_mfma_f16a(const f16* __restrict__ A, const float* __restrict__ W,
                                 const float* __restrict__ dinv, f16* __restrict__ Hh, int M){
  constexpr int BM = 128, BK = 32, BN = N;
  constexpr int AST = 40;
  constexpr int NM = 4;
  constexpr int NN = BN/32;               // 2 for BN=64
  constexpr int SKN = BK*BN/THREADS;      // 8
  __shared__ f16 Ah[BM*AST], Bh[BN*AST], Bl[BN*AST];

  const int tid  = threadIdx.x;
  const int row0 = blockIdx.x*BM;
  const int wv = tid>>6, l = tid&63;
  const int wr = wv>>1, wc = wv&1;
  const int lr = l&15, lk = l>>4;

  const int sar = tid>>1, sak = (tid&1)*16;
  const long long garow = min(row0+sar, M-1);
  const int sc = tid % BN, sk0 = (tid/BN)*SKN;

  f32x4 acc[NM][NN] = {};

  for(int k0 = 0; k0 < K; k0 += BK){
    f16x8 av[2];
    av[0] = *(const f16x8*)(A + garow*K + k0 + sak);
    av[1] = *(const f16x8*)(A + garow*K + k0 + sak + 8);
    float bvals[SKN];
    #pragma unroll
    for(int i=0;i<SKN;i++) bvals[i] = W[(size_t)(k0+sk0+i)*N + sc];

    __syncthreads();

    *(f16x8*)&Ah[sar*AST + sak]     = av[0];
    *(f16x8*)&Ah[sar*AST + sak + 8] = av[1];
    #pragma unroll
    for(int s=0;s<SKN/8;s++){
      f16x8 hi, lo;
      #pragma unroll
      for(int j=0;j<8;j++){
        float x = bvals[s*8+j];
        f16 h = (f16)x;
        hi[j] = h; lo[j] = (f16)(x - (float)h);
      }
      *(f16x8*)&Bh[sc*AST + sk0 + s*8] = hi;
      *(f16x8*)&Bl[sc*AST + sk0 + s*8] = lo;
    }
    __syncthreads();

    f16x8 af[NM], bfh[NN], bfl[NN];
    #pragma unroll
    for(int m=0;m<NM;m++){
      int r = wr*64 + m*16 + lr;
      af[m] = *(const f16x8*)&Ah[r*AST + lk*8];
    }
    #pragma unroll
    for(int n=0;n<NN;n++){
      int c = wc*(BN/2) + n*16 + lr;
      bfh[n] = *(const f16x8*)&Bh[c*AST + lk*8];
      bfl[n] = *(const f16x8*)&Bl[c*AST + lk*8];
    }
    #pragma unroll
    for(int m=0;m<NM;m++)
      #pragma unroll
      for(int n=0;n<NN;n++){
        acc[m][n] = __builtin_amdgcn_mfma_f32_16x16x32_f16(af[m], bfh[n], acc[m][n], 0,0,0);
        acc[m][n] = __builtin_amdgcn_mfma_f32_16x16x32_f16(af[m], bfl[n], acc[m][n], 0,0,0);
      }
  }

  #pragma unroll
  for(int m=0;m<NM;m++){
    int grb = row0 + wr*64 + m*16 + lk*4;
    #pragma unroll
    for(int reg=0;reg<4;reg++){
      int gr = grb + reg;
      if(gr < M){
        float dv = dinv[gr];
        #pragma unroll
        for(int n=0;n<NN;n++){
          int gc = wc*(BN/2) + n*16 + lr;
          Hh[(size_t)gr*N + gc] = (f16)(acc[m][n][reg] * dv);
        }
      }
    }
  }
}

// gather, NC=128, f16 in / f16 out, ReLU fused: one wave per node.
__global__ void k_gather_l1(const int* __restrict__ off, const int* __restrict__ ssrc,
                            const f16* __restrict__ g, const float* __restrict__ dinv,
                            const float* __restrict__ bias, f16* __restrict__ outh, int M){
  const int w    = (blockIdx.x * blockDim.x + threadIdx.x) >> 6;
  const int lane = threadIdx.x & 63;
  if(w >= M) return;
  const f16x2* g2 = (const f16x2*)g;
  f16x2 sv = g2[(size_t)w*64 + lane];
  float ax = (float)sv[0], ay = (float)sv[1];
  const int e0 = off[w], e1 = off[w+1];
  int i = e0;
  for(; i+1 < e1; i += 2){
    int s0 = ssrc[i], s1 = ssrc[i+1];
    f16x2 v0 = g2[(size_t)s0*64 + lane];
    f16x2 v1 = g2[(size_t)s1*64 + lane];
    ax += (float)v0[0] + (float)v1[0];
    ay += (float)v0[1] + (float)v1[1];
  }
  if(i < e1){
    f16x2 v = g2[(size_t)ssrc[i]*64 + lane];
    ax += (float)v[0]; ay += (float)v[1];
  }
  const float dd = dinv[w];
  float2 bb = ((const float2*)bias)[lane];
  float ox = fmaxf(fmaf(ax, dd, bb.x), 0.f);
  float oy = fmaxf(fmaf(ay, dd, bb.y), 0.f);
  f16x2 o; o[0] = (f16)ox; o[1] = (f16)oy;
  ((f16x2*)outh)[(size_t)w*64 + lane] = o;
}

// gather, NC=64, f16 in / f32 out (final): 32-lane half-wave per node.
__global__ void k_gather_l2(const int* __restrict__ off, const int* __restrict__ ssrc,
                            const f16* __restrict__ g, const float* __restrict__ dinv,
                            const float* __restrict__ bias, float* __restrict__ out, int M){
  const int id   = blockIdx.x * blockDim.x + threadIdx.x;
  const int w    = id >> 5;
  const int l32  = id & 31;
  if(w >= M) return;
  const f16x2* g2 = (const f16x2*)g;
  f16x2 sv = g2[(size_t)w*32 + l32];
  float ax = (float)sv[0], ay = (float)sv[1];
  const int e0 = off[w], e1 = off[w+1];
  int i = e0;
  for(; i+1 < e1; i += 2){
    int s0 = ssrc[i], s1 = ssrc[i+1];
    f16x2 v0 = g2[(size_t)s0*32 + l32];
    f16x2 v1 = g2[(size_t)s1*32 + l32];
    ax += (float)v0[0] + (float)v1[0];
    ay += (float)v0[1] + (float)v1[1];
  }
  if(i < e1){
    f16x2 v = g2[(size_t)ssrc[i]*32 + l32];
    ax += (float)v[0]; ay += (float)v[1];
  }
  const float dd = dinv[w];
  float2 bb = ((const float2*)bias)[l32];
  float2 o;
  o.x = fmaf(ax, dd, bb.x);
  o.y = fmaf(ay, dd, bb.y);
  ((float2*)out)[(size_t)w*32 + l32] = o;
}

extern "C" void kernel_launch(void* const* d_in, const int* in_sizes, int n_in,
                              void* d_out, int out_size, void* d_ws, size_t ws_size,
                              hipStream_t stream){
  const float* feat = (const float*)d_in[0];
  const int*   ei   = (const int*)d_in[1];
  const float* W1   = (const float*)d_in[2];
  const float* b1   = (const float*)d_in[3];
  const float* W2   = (const float*)d_in[4];
  const float* b2   = (const float*)d_in[5];
  float* out = (float*)d_out;

  const int M = in_sizes[0] / 256;   // 50000 nodes
  const int E = in_sizes[1] / 2;     // 800000 edges

  float* ws = (float*)d_ws;
  unsigned* cnt  = (unsigned*)ws;             // [0, 50176)
  float*    dinv = ws + 50176;                // [50176, 100352)
  int*      off  = (int*)(ws + 100352);       // 50001 ints
  int*      curs = (int*)(ws + 150656);       // 50176 ints
  int*      part = (int*)(ws + 200832);       // 64 ints
  int*      ssrc = (int*)(ws + 200960);       // 800000 ints
  f16*      h1h  = (f16*)(ws + 1000960);      // M*128 f16
  f16*      o1h  = (f16*)(ws + 4200960);      // M*128 f16
  f16*      h2h  = h1h;                       // reuse (dead after gather1)

  const int nbN = (M + THREADS-1)/THREADS;
  const int nbE = (E + THREADS-1)/THREADS;
  const int nbScan = (M + 1023)/1024;         // 49

  // CSR build (dst-sorted)
  k_zero_cnt<<<nbN, THREADS, 0, stream>>>(cnt, M);
  k_count<<<nbE, THREADS, 0, stream>>>(ei + E, cnt, E);
  k_scan_local<<<nbScan, 256, 0, stream>>>(cnt, off, part, M);
  k_scan_part<<<1, 64, 0, stream>>>(part, nbScan);
  k_scan_add<<<nbN, THREADS, 0, stream>>>(cnt, off, part, dinv, curs, M, E);
  k_build<<<nbE*8, THREADS, 0, stream>>>(ei, curs, ssrc, E, M);

  const int gemmBlocks = (M + 127)/128;

  // ----- layer 1: 256 -> 128 -----
  k_gemm_mfma_f32<256,128><<<gemmBlocks, THREADS, 0, stream>>>(feat, W1, dinv, h1h, M);
  k_gather_l1<<<(M*64 + THREADS-1)/THREADS, THREADS, 0, stream>>>(off, ssrc, h1h, dinv, b1, o1h, M);

  // ----- layer 2: 128 -> 64 -----
  k_gemm_mfma_f16a<128,64><<<gemmBlocks, THREADS, 0, stream>>>(o1h, W2, dinv, h2h, M);
  k_gather_l2<<<(M*32 + THREADS-1)/THREADS, THREADS, 0, stream>>>(off, ssrc, h2h, dinv, b2, out, M);
}

// Round 10
// 187.108 us; speedup vs baseline: 1.6958x; 1.1514x over previous
//
#include <hip/hip_runtime.h>

#define THREADS 256

typedef _Float16 f16;
typedef f16   f16x8 __attribute__((ext_vector_type(8)));
typedef float f32x4 __attribute__((ext_vector_type(4)));

// ---- hierarchical exclusive scan over cnt[0..M) ----
__global__ void k_scan_local(const unsigned* __restrict__ cnt, int* __restrict__ off,
                             int* __restrict__ partials, int M){
  __shared__ int ts[256];
  const int t = threadIdx.x;
  const int base = blockIdx.x*1024 + t*4;
  int4 v = make_int4(0,0,0,0);
  if(base+3 < M) v = *(const int4*)(cnt+base);
  else {
    if(base+0<M) v.x=(int)cnt[base+0];
    if(base+1<M) v.y=(int)cnt[base+1];
    if(base+2<M) v.z=(int)cnt[base+2];
  }
  ts[t] = v.x+v.y+v.z+v.w;
  __syncthreads();
  for(int o=1;o<256;o<<=1){
    int u = (t>=o)? ts[t-o] : 0;
    __syncthreads();
    ts[t] += u;
    __syncthreads();
  }
  int ex = (t==0)? 0 : ts[t-1];
  if(base+0<M) off[base+0] = ex;
  if(base+1<M) off[base+1] = ex + v.x;
  if(base+2<M) off[base+2] = ex + v.x + v.y;
  if(base+3<M) off[base+3] = ex + v.x + v.y + v.z;
  if(t==255) partials[blockIdx.x] = ts[255];
}

// scan_add with the partials-scan folded in (wave 0 of each block redoes the
// 49-element scan; saves a kernel launch).
__global__ void k_scan_add(const unsigned* __restrict__ cnt, int* __restrict__ off,
                           const int* __restrict__ partials, float* __restrict__ dinv,
                           int* __restrict__ cursor, int M, int E, int NB){
  __shared__ int sp[64];
  const int t = threadIdx.x;
  if(t < 64){
    int v = (t<NB)? partials[t] : 0;
    int s = v;
    for(int o=1;o<64;o<<=1){
      int u = __shfl_up(s, o);
      if(t >= o) s += u;
    }
    sp[t] = s;                     // inclusive scan
  }
  __syncthreads();
  int i = blockIdx.x*blockDim.x + t;
  if(i < M){
    int g = i>>10;
    int o = off[i] + (g==0 ? 0 : sp[g-1]);
    off[i] = o;
    cursor[i] = o;
    dinv[i] = rsqrtf((float)(cnt[i] + 1u));  // +1 self-loop
  }
  if(i == 0) off[M] = E;
}

// dst-range-partitioned build (one XCD owns each ssrc window -> no line ping-pong)
__global__ void k_build(const int* __restrict__ ei, int* __restrict__ cursor,
                        int* __restrict__ ssrc, int E, int M){
  const int grp = blockIdx.x & 7;
  const int nb  = blockIdx.x >> 3;
  const int lo  = grp * (M >> 3);
  const int hi  = (grp == 7) ? M : lo + (M >> 3);
  int e = nb*THREADS + threadIdx.x;
  if(e < E){
    int d = ei[E+e];
    if(d >= lo && d < hi){
      int s = ei[e];
      int p = atomicAdd(&cursor[d], 1);
      ssrc[p] = s;
    }
  }
}

// ---- fused: MFMA GEMM layer1 (f32 hi/lo split, UNSCALED f16 out)  ||  degree count ----
template<int K, int N>
__global__ void k_gemm1_count(const float* __restrict__ A, const float* __restrict__ W,
                              f16* __restrict__ Hh, int M,
                              const int* __restrict__ dst, unsigned* __restrict__ cnt,
                              int E, int gemmBlocks, int cntStride){
  constexpr int BM = 128, BK = 32, BN = N;
  constexpr int AST = 40;
  constexpr int NM = 4;
  constexpr int NN = BN/32;
  constexpr int SKN = BK*BN/THREADS;
  __shared__ f16 Ah[BM*AST], Al[BM*AST], Bh[BN*AST], Bl[BN*AST];

  if((int)blockIdx.x >= gemmBlocks){
    // ---- degree-count blocks (grid-stride over edges) ----
    int e = ((int)blockIdx.x - gemmBlocks)*THREADS + threadIdx.x;
    for(; e < E; e += cntStride) atomicAdd(&cnt[dst[e]], 1u);
    return;
  }

  const int tid  = threadIdx.x;
  const int row0 = blockIdx.x*BM;
  const int wv = tid>>6, l = tid&63;
  const int wr = wv>>1, wc = wv&1;
  const int lr = l&15, lk = l>>4;

  const int sar = tid>>1, sak = (tid&1)*16;
  const long long garow = min(row0+sar, M-1);
  const int sc = tid % BN, sk0 = (tid/BN)*SKN;

  f32x4 acc[NM][NN] = {};

  for(int k0 = 0; k0 < K; k0 += BK){
    float avals[16];
    #pragma unroll
    for(int q=0;q<4;q++){
      float4 v = *(const float4*)(A + garow*K + k0 + sak + q*4);
      avals[q*4+0]=v.x; avals[q*4+1]=v.y; avals[q*4+2]=v.z; avals[q*4+3]=v.w;
    }
    float bvals[SKN];
    #pragma unroll
    for(int i=0;i<SKN;i++) bvals[i] = W[(size_t)(k0+sk0+i)*N + sc];

    __syncthreads();

    #pragma unroll
    for(int s=0;s<2;s++){
      f16x8 hi, lo;
      #pragma unroll
      for(int j=0;j<8;j++){
        float x = avals[s*8+j];
        f16 h = (f16)x;
        hi[j] = h; lo[j] = (f16)(x - (float)h);
      }
      *(f16x8*)&Ah[sar*AST + sak + s*8] = hi;
      *(f16x8*)&Al[sar*AST + sak + s*8] = lo;
    }
    #pragma unroll
    for(int s=0;s<SKN/8;s++){
      f16x8 hi, lo;
      #pragma unroll
      for(int j=0;j<8;j++){
        float x = bvals[s*8+j];
        f16 h = (f16)x;
        hi[j] = h; lo[j] = (f16)(x - (float)h);
      }
      *(f16x8*)&Bh[sc*AST + sk0 + s*8] = hi;
      *(f16x8*)&Bl[sc*AST + sk0 + s*8] = lo;
    }
    __syncthreads();

    f16x8 afh[NM], afl[NM], bfh[NN], bfl[NN];
    #pragma unroll
    for(int m=0;m<NM;m++){
      int r = wr*64 + m*16 + lr;
      afh[m] = *(const f16x8*)&Ah[r*AST + lk*8];
      afl[m] = *(const f16x8*)&Al[r*AST + lk*8];
    }
    #pragma unroll
    for(int n=0;n<NN;n++){
      int c = wc*(BN/2) + n*16 + lr;
      bfh[n] = *(const f16x8*)&Bh[c*AST + lk*8];
      bfl[n] = *(const f16x8*)&Bl[c*AST + lk*8];
    }
    #pragma unroll
    for(int m=0;m<NM;m++)
      #pragma unroll
      for(int n=0;n<NN;n++){
        acc[m][n] = __builtin_amdgcn_mfma_f32_16x16x32_f16(afh[m], bfh[n], acc[m][n], 0,0,0);
        acc[m][n] = __builtin_amdgcn_mfma_f32_16x16x32_f16(afh[m], bfl[n], acc[m][n], 0,0,0);
        acc[m][n] = __builtin_amdgcn_mfma_f32_16x16x32_f16(afl[m], bfh[n], acc[m][n], 0,0,0);
      }
  }

  #pragma unroll
  for(int m=0;m<NM;m++){
    int grb = row0 + wr*64 + m*16 + lk*4;
    #pragma unroll
    for(int reg=0;reg<4;reg++){
      int gr = grb + reg;
      if(gr < M){
        #pragma unroll
        for(int n=0;n<NN;n++){
          int gc = wc*(BN/2) + n*16 + lr;
          Hh[(size_t)gr*N + gc] = (f16)(acc[m][n][reg]);   // unscaled
        }
      }
    }
  }
}

// ---- MFMA GEMM, f16 A (no A split), f32 W hi/lo split, f16 out scaled by dinv ----
template<int K, int N>
__global__ void k_gemm_mfma_f16a(const f16* __restrict__ A, const float* __restrict__ W,
                                 const float* __restrict__ dinv, f16* __restrict__ Hh, int M){
  constexpr int BM = 128, BK = 32, BN = N;
  constexpr int AST = 40;
  constexpr int NM = 4;
  constexpr int NN = BN/32;
  constexpr int SKN = BK*BN/THREADS;
  __shared__ f16 Ah[BM*AST], Bh[BN*AST], Bl[BN*AST];

  const int tid  = threadIdx.x;
  const int row0 = blockIdx.x*BM;
  const int wv = tid>>6, l = tid&63;
  const int wr = wv>>1, wc = wv&1;
  const int lr = l&15, lk = l>>4;

  const int sar = tid>>1, sak = (tid&1)*16;
  const long long garow = min(row0+sar, M-1);
  const int sc = tid % BN, sk0 = (tid/BN)*SKN;

  f32x4 acc[NM][NN] = {};

  for(int k0 = 0; k0 < K; k0 += BK){
    f16x8 av[2];
    av[0] = *(const f16x8*)(A + garow*K + k0 + sak);
    av[1] = *(const f16x8*)(A + garow*K + k0 + sak + 8);
    float bvals[SKN];
    #pragma unroll
    for(int i=0;i<SKN;i++) bvals[i] = W[(size_t)(k0+sk0+i)*N + sc];

    __syncthreads();

    *(f16x8*)&Ah[sar*AST + sak]     = av[0];
    *(f16x8*)&Ah[sar*AST + sak + 8] = av[1];
    #pragma unroll
    for(int s=0;s<SKN/8;s++){
      f16x8 hi, lo;
      #pragma unroll
      for(int j=0;j<8;j++){
        float x = bvals[s*8+j];
        f16 h = (f16)x;
        hi[j] = h; lo[j] = (f16)(x - (float)h);
      }
      *(f16x8*)&Bh[sc*AST + sk0 + s*8] = hi;
      *(f16x8*)&Bl[sc*AST + sk0 + s*8] = lo;
    }
    __syncthreads();

    f16x8 af[NM], bfh[NN], bfl[NN];
    #pragma unroll
    for(int m=0;m<NM;m++){
      int r = wr*64 + m*16 + lr;
      af[m] = *(const f16x8*)&Ah[r*AST + lk*8];
    }
    #pragma unroll
    for(int n=0;n<NN;n++){
      int c = wc*(BN/2) + n*16 + lr;
      bfh[n] = *(const f16x8*)&Bh[c*AST + lk*8];
      bfl[n] = *(const f16x8*)&Bl[c*AST + lk*8];
    }
    #pragma unroll
    for(int m=0;m<NM;m++)
      #pragma unroll
      for(int n=0;n<NN;n++){
        acc[m][n] = __builtin_amdgcn_mfma_f32_16x16x32_f16(af[m], bfh[n], acc[m][n], 0,0,0);
        acc[m][n] = __builtin_amdgcn_mfma_f32_16x16x32_f16(af[m], bfl[n], acc[m][n], 0,0,0);
      }
  }

  #pragma unroll
  for(int m=0;m<NM;m++){
    int grb = row0 + wr*64 + m*16 + lk*4;
    #pragma unroll
    for(int reg=0;reg<4;reg++){
      int gr = grb + reg;
      if(gr < M){
        float dv = dinv[gr];
        #pragma unroll
        for(int n=0;n<NN;n++){
          int gc = wc*(BN/2) + n*16 + lr;
          Hh[(size_t)gr*N + gc] = (f16)(acc[m][n][reg] * dv);
        }
      }
    }
  }
}

// gather layer1: wave per node; 16 lanes x f16x8 cover the 128-col row, so each
// wave-instruction fetches FOUR edges' rows (quarter q handles edge i+q).
// h is UNSCALED -> per-edge fma with dinv[src]; epilogue: *dinv[w] + b, relu, f16.
__global__ void k_gather_l1(const int* __restrict__ off, const int* __restrict__ ssrc,
                            const f16* __restrict__ g, const float* __restrict__ dinv,
                            const float* __restrict__ bias, f16* __restrict__ outh, int M){
  const int w = (blockIdx.x*blockDim.x + threadIdx.x) >> 6;
  const int l = threadIdx.x & 63;
  if(w >= M) return;
  const int q = l>>4, c = l&15;
  const f16x8* g8 = (const f16x8*)g;        // row stride = 16 f16x8
  float acc[8] = {0.f,0.f,0.f,0.f,0.f,0.f,0.f,0.f};
  const int e0 = off[w], e1 = off[w+1];
  const int ne = e1 - e0;
  int i = e0 + q;
  for(int it = ne>>2; it>0; --it, i+=4){
    int s = ssrc[i];
    float ds = dinv[s];
    f16x8 v = g8[(size_t)s*16 + c];
    #pragma unroll
    for(int j=0;j<8;j++) acc[j] = fmaf((float)v[j], ds, acc[j]);
  }
  if(q < (ne & 3)){
    int s = ssrc[i];
    float ds = dinv[s];
    f16x8 v = g8[(size_t)s*16 + c];
    #pragma unroll
    for(int j=0;j<8;j++) acc[j] = fmaf((float)v[j], ds, acc[j]);
  }
  const float dw = dinv[w];
  if(q == 0){                                // self-loop term
    f16x8 v = g8[(size_t)w*16 + c];
    #pragma unroll
    for(int j=0;j<8;j++) acc[j] = fmaf((float)v[j], dw, acc[j]);
  }
  #pragma unroll
  for(int j=0;j<8;j++){
    acc[j] += __shfl_xor(acc[j], 16);
    acc[j] += __shfl_xor(acc[j], 32);
  }
  if(q == 0){
    float4 b0 = ((const float4*)bias)[c*2];
    float4 b1 = ((const float4*)bias)[c*2+1];
    f16x8 o;
    o[0] = (f16)fmaxf(fmaf(acc[0], dw, b0.x), 0.f);
    o[1] = (f16)fmaxf(fmaf(acc[1], dw, b0.y), 0.f);
    o[2] = (f16)fmaxf(fmaf(acc[2], dw, b0.z), 0.f);
    o[3] = (f16)fmaxf(fmaf(acc[3], dw, b0.w), 0.f);
    o[4] = (f16)fmaxf(fmaf(acc[4], dw, b1.x), 0.f);
    o[5] = (f16)fmaxf(fmaf(acc[5], dw, b1.y), 0.f);
    o[6] = (f16)fmaxf(fmaf(acc[6], dw, b1.z), 0.f);
    o[7] = (f16)fmaxf(fmaf(acc[7], dw, b1.w), 0.f);
    ((f16x8*)outh)[(size_t)w*16 + c] = o;
  }
}

// gather layer2: wave per node; 8 lanes x f16x8 cover the 64-col row -> EIGHT
// edges per wave-instruction. g (h2h) is pre-scaled by dinv[src]; f32 output.
__global__ void k_gather_l2(const int* __restrict__ off, const int* __restrict__ ssrc,
                            const f16* __restrict__ g, const float* __restrict__ dinv,
                            const float* __restrict__ bias, float* __restrict__ out, int M){
  const int w = (blockIdx.x*blockDim.x + threadIdx.x) >> 6;
  const int l = threadIdx.x & 63;
  if(w >= M) return;
  const int grp = l>>3, c = l&7;
  const f16x8* g8 = (const f16x8*)g;        // row stride = 8 f16x8
  float acc[8] = {0.f,0.f,0.f,0.f,0.f,0.f,0.f,0.f};
  const int e0 = off[w], e1 = off[w+1];
  const int ne = e1 - e0;
  int i = e0 + grp;
  for(int it = ne>>3; it>0; --it, i+=8){
    int s = ssrc[i];
    f16x8 v = g8[(size_t)s*8 + c];
    #pragma unroll
    for(int j=0;j<8;j++) acc[j] += (float)v[j];
  }
  if(grp < (ne & 7)){
    int s = ssrc[i];
    f16x8 v = g8[(size_t)s*8 + c];
    #pragma unroll
    for(int j=0;j<8;j++) acc[j] += (float)v[j];
  }
  if(grp == 0){                              // self-loop (already *dinv[w])
    f16x8 v = g8[(size_t)w*8 + c];
    #pragma unroll
    for(int j=0;j<8;j++) acc[j] += (float)v[j];
  }
  #pragma unroll
  for(int j=0;j<8;j++){
    acc[j] += __shfl_xor(acc[j], 8);
    acc[j] += __shfl_xor(acc[j], 16);
    acc[j] += __shfl_xor(acc[j], 32);
  }
  if(grp == 0){
    const float dw = dinv[w];
    float4 b0 = ((const float4*)bias)[c*2];
    float4 b1 = ((const float4*)bias)[c*2+1];
    float4 o0, o1;
    o0.x = fmaf(acc[0], dw, b0.x);
    o0.y = fmaf(acc[1], dw, b0.y);
    o0.z = fmaf(acc[2], dw, b0.z);
    o0.w = fmaf(acc[3], dw, b0.w);
    o1.x = fmaf(acc[4], dw, b1.x);
    o1.y = fmaf(acc[5], dw, b1.y);
    o1.z = fmaf(acc[6], dw, b1.z);
    o1.w = fmaf(acc[7], dw, b1.w);
    ((float4*)out)[(size_t)w*16 + c*2]     = o0;
    ((float4*)out)[(size_t)w*16 + c*2 + 1] = o1;
  }
}

extern "C" void kernel_launch(void* const* d_in, const int* in_sizes, int n_in,
                              void* d_out, int out_size, void* d_ws, size_t ws_size,
                              hipStream_t stream){
  const float* feat = (const float*)d_in[0];
  const int*   ei   = (const int*)d_in[1];
  const float* W1   = (const float*)d_in[2];
  const float* b1   = (const float*)d_in[3];
  const float* W2   = (const float*)d_in[4];
  const float* b2   = (const float*)d_in[5];
  float* out = (float*)d_out;

  const int M = in_sizes[0] / 256;   // 50000 nodes
  const int E = in_sizes[1] / 2;     // 800000 edges

  float* ws = (float*)d_ws;
  unsigned* cnt  = (unsigned*)ws;             // [0, 50176)
  float*    dinv = ws + 50176;                // [50176, 100352)
  int*      off  = (int*)(ws + 100352);       // 50001 ints
  int*      curs = (int*)(ws + 150656);       // 50176 ints
  int*      part = (int*)(ws + 200832);       // 64 ints
  int*      ssrc = (int*)(ws + 200960);       // 800000 ints
  f16*      h1h  = (f16*)(ws + 1000960);      // M*128 f16
  f16*      o1h  = (f16*)(ws + 4200960);      // M*128 f16
  f16*      h2h  = h1h;                       // reuse (dead after gather1)

  const int nbN = (M + THREADS-1)/THREADS;
  const int nbE = (E + THREADS-1)/THREADS;
  const int nbScan = (M + 1023)/1024;         // 49
  const int gemmBlocks = (M + 127)/128;       // 391
  const int CNT_BLOCKS = 1024;

  hipMemsetAsync(cnt, 0, (size_t)M*sizeof(unsigned), stream);

  // fused: layer-1 GEMM (MFMA-bound) overlapped with degree count (atomic-bound)
  k_gemm1_count<256,128><<<gemmBlocks + CNT_BLOCKS, THREADS, 0, stream>>>(
      feat, W1, h1h, M, ei + E, cnt, E, gemmBlocks, CNT_BLOCKS*THREADS);

  k_scan_local<<<nbScan, 256, 0, stream>>>(cnt, off, part, M);
  k_scan_add<<<nbN, THREADS, 0, stream>>>(cnt, off, part, dinv, curs, M, E, nbScan);
  k_build<<<nbE*8, THREADS, 0, stream>>>(ei, curs, ssrc, E, M);

  k_gather_l1<<<(M*64 + THREADS-1)/THREADS, THREADS, 0, stream>>>(off, ssrc, h1h, dinv, b1, o1h, M);

  k_gemm_mfma_f16a<128,64><<<gemmBlocks, THREADS, 0, stream>>>(o1h, W2, dinv, h2h, M);
  k_gather_l2<<<(M*64 + THREADS-1)/THREADS, THREADS, 0, stream>>>(off, ssrc, h2h, dinv, b2, out, M);
}

// Round 11
// 178.130 us; speedup vs baseline: 1.7813x; 1.0504x over previous
//
#include <hip/hip_runtime.h>

#define THREADS 256

typedef _Float16 f16;
typedef f16   f16x8 __attribute__((ext_vector_type(8)));
typedef float f32x4 __attribute__((ext_vector_type(4)));

// ---- hierarchical exclusive scan over cnt[0..M) ----
__global__ void k_scan_local(const unsigned* __restrict__ cnt, int* __restrict__ off,
                             int* __restrict__ partials, int M){
  __shared__ int ts[256];
  const int t = threadIdx.x;
  const int base = blockIdx.x*1024 + t*4;
  int4 v = make_int4(0,0,0,0);
  if(base+3 < M) v = *(const int4*)(cnt+base);
  else {
    if(base+0<M) v.x=(int)cnt[base+0];
    if(base+1<M) v.y=(int)cnt[base+1];
    if(base+2<M) v.z=(int)cnt[base+2];
  }
  ts[t] = v.x+v.y+v.z+v.w;
  __syncthreads();
  for(int o=1;o<256;o<<=1){
    int u = (t>=o)? ts[t-o] : 0;
    __syncthreads();
    ts[t] += u;
    __syncthreads();
  }
  int ex = (t==0)? 0 : ts[t-1];
  if(base+0<M) off[base+0] = ex;
  if(base+1<M) off[base+1] = ex + v.x;
  if(base+2<M) off[base+2] = ex + v.x + v.y;
  if(base+3<M) off[base+3] = ex + v.x + v.y + v.z;
  if(t==255) partials[blockIdx.x] = ts[255];
}

// scan_add with the partials-scan folded in
__global__ void k_scan_add(const unsigned* __restrict__ cnt, int* __restrict__ off,
                           const int* __restrict__ partials, float* __restrict__ dinv,
                           int* __restrict__ cursor, int M, int E, int NB){
  __shared__ int sp[64];
  const int t = threadIdx.x;
  if(t < 64){
    int v = (t<NB)? partials[t] : 0;
    int s = v;
    for(int o=1;o<64;o<<=1){
      int u = __shfl_up(s, o);
      if(t >= o) s += u;
    }
    sp[t] = s;                     // inclusive scan
  }
  __syncthreads();
  int i = blockIdx.x*blockDim.x + t;
  if(i < M){
    int g = i>>10;
    int o = off[i] + (g==0 ? 0 : sp[g-1]);
    off[i] = o;
    cursor[i] = o;
    dinv[i] = rsqrtf((float)(cnt[i] + 1u));  // +1 self-loop
  }
  if(i == 0) off[M] = E;
}

// dst-range-partitioned build (one XCD owns each ssrc window -> no line ping-pong)
__global__ void k_build(const int* __restrict__ ei, int* __restrict__ cursor,
                        int* __restrict__ ssrc, int E, int M){
  const int grp = blockIdx.x & 7;
  const int nb  = blockIdx.x >> 3;
  const int lo  = grp * (M >> 3);
  const int hi  = (grp == 7) ? M : lo + (M >> 3);
  int e = nb*THREADS + threadIdx.x;
  if(e < E){
    int d = ei[E+e];
    if(d >= lo && d < hi){
      int s = ei[e];
      int p = atomicAdd(&cursor[d], 1);
      ssrc[p] = s;
    }
  }
}

// ---- fused: MFMA GEMM layer1 (f32 hi/lo split, UNSCALED f16 out) || dst-partitioned degree count ----
template<int K, int N>
__global__ void k_gemm1_count(const float* __restrict__ A, const float* __restrict__ W,
                              f16* __restrict__ Hh, int M,
                              const int* __restrict__ dst, unsigned* __restrict__ cnt,
                              int E, int gemmBlocks, int cntBlocks){
  constexpr int BM = 128, BK = 32, BN = N;
  constexpr int AST = 40;
  constexpr int NM = 4;
  constexpr int NN = BN/32;
  constexpr int SKN = BK*BN/THREADS;
  __shared__ f16 Ah[BM*AST], Al[BM*AST], Bh[BN*AST], Bl[BN*AST];

  if((int)blockIdx.x >= gemmBlocks){
    // ---- degree-count blocks: absolute blockIdx&7 -> XCD-affine dst range ----
    const int grp = blockIdx.x & 7;
    const int lo  = grp * (M >> 3);
    const int hi  = (grp == 7) ? M : lo + (M >> 3);
    const int bi  = (int)blockIdx.x - gemmBlocks;
    const int j   = bi >> 3;                 // block index within group
    const int stride = (cntBlocks >> 3) * THREADS;
    for(int e = j*THREADS + (int)threadIdx.x; e < E; e += stride){
      int d = dst[e];
      if(d >= lo && d < hi) atomicAdd(&cnt[d], 1u);
    }
    return;
  }

  const int tid  = threadIdx.x;
  const int row0 = blockIdx.x*BM;
  const int wv = tid>>6, l = tid&63;
  const int wr = wv>>1, wc = wv&1;
  const int lr = l&15, lk = l>>4;

  const int sar = tid>>1, sak = (tid&1)*16;
  const long long garow = min(row0+sar, M-1);
  const int sc = tid % BN, sk0 = (tid/BN)*SKN;

  f32x4 acc[NM][NN] = {};

  for(int k0 = 0; k0 < K; k0 += BK){
    float avals[16];
    #pragma unroll
    for(int q=0;q<4;q++){
      float4 v = *(const float4*)(A + garow*K + k0 + sak + q*4);
      avals[q*4+0]=v.x; avals[q*4+1]=v.y; avals[q*4+2]=v.z; avals[q*4+3]=v.w;
    }
    float bvals[SKN];
    #pragma unroll
    for(int i=0;i<SKN;i++) bvals[i] = W[(size_t)(k0+sk0+i)*N + sc];

    __syncthreads();

    #pragma unroll
    for(int s=0;s<2;s++){
      f16x8 hi, lo;
      #pragma unroll
      for(int j=0;j<8;j++){
        float x = avals[s*8+j];
        f16 h = (f16)x;
        hi[j] = h; lo[j] = (f16)(x - (float)h);
      }
      *(f16x8*)&Ah[sar*AST + sak + s*8] = hi;
      *(f16x8*)&Al[sar*AST + sak + s*8] = lo;
    }
    #pragma unroll
    for(int s=0;s<SKN/8;s++){
      f16x8 hi, lo;
      #pragma unroll
      for(int j=0;j<8;j++){
        float x = bvals[s*8+j];
        f16 h = (f16)x;
        hi[j] = h; lo[j] = (f16)(x - (float)h);
      }
      *(f16x8*)&Bh[sc*AST + sk0 + s*8] = hi;
      *(f16x8*)&Bl[sc*AST + sk0 + s*8] = lo;
    }
    __syncthreads();

    f16x8 afh[NM], afl[NM], bfh[NN], bfl[NN];
    #pragma unroll
    for(int m=0;m<NM;m++){
      int r = wr*64 + m*16 + lr;
      afh[m] = *(const f16x8*)&Ah[r*AST + lk*8];
      afl[m] = *(const f16x8*)&Al[r*AST + lk*8];
    }
    #pragma unroll
    for(int n=0;n<NN;n++){
      int c = wc*(BN/2) + n*16 + lr;
      bfh[n] = *(const f16x8*)&Bh[c*AST + lk*8];
      bfl[n] = *(const f16x8*)&Bl[c*AST + lk*8];
    }
    #pragma unroll
    for(int m=0;m<NM;m++)
      #pragma unroll
      for(int n=0;n<NN;n++){
        acc[m][n] = __builtin_amdgcn_mfma_f32_16x16x32_f16(afh[m], bfh[n], acc[m][n], 0,0,0);
        acc[m][n] = __builtin_amdgcn_mfma_f32_16x16x32_f16(afh[m], bfl[n], acc[m][n], 0,0,0);
        acc[m][n] = __builtin_amdgcn_mfma_f32_16x16x32_f16(afl[m], bfh[n], acc[m][n], 0,0,0);
      }
  }

  #pragma unroll
  for(int m=0;m<NM;m++){
    int grb = row0 + wr*64 + m*16 + lk*4;
    #pragma unroll
    for(int reg=0;reg<4;reg++){
      int gr = grb + reg;
      if(gr < M){
        #pragma unroll
        for(int n=0;n<NN;n++){
          int gc = wc*(BN/2) + n*16 + lr;
          Hh[(size_t)gr*N + gc] = (f16)(acc[m][n][reg]);   // unscaled
        }
      }
    }
  }
}

// ---- MFMA GEMM, f16 A (no A split), f32 W hi/lo split, f16 out scaled by dinv ----
template<int K, int N>
__global__ void k_gemm_mfma_f16a(const f16* __restrict__ A, const float* __restrict__ W,
                                 const float* __restrict__ dinv, f16* __restrict__ Hh, int M){
  constexpr int BM = 128, BK = 32, BN = N;
  constexpr int AST = 40;
  constexpr int NM = 4;
  constexpr int NN = BN/32;
  constexpr int SKN = BK*BN/THREADS;
  __shared__ f16 Ah[BM*AST], Bh[BN*AST], Bl[BN*AST];

  const int tid  = threadIdx.x;
  const int row0 = blockIdx.x*BM;
  const int wv = tid>>6, l = tid&63;
  const int wr = wv>>1, wc = wv&1;
  const int lr = l&15, lk = l>>4;

  const int sar = tid>>1, sak = (tid&1)*16;
  const long long garow = min(row0+sar, M-1);
  const int sc = tid % BN, sk0 = (tid/BN)*SKN;

  f32x4 acc[NM][NN] = {};

  for(int k0 = 0; k0 < K; k0 += BK){
    f16x8 av[2];
    av[0] = *(const f16x8*)(A + garow*K + k0 + sak);
    av[1] = *(const f16x8*)(A + garow*K + k0 + sak + 8);
    float bvals[SKN];
    #pragma unroll
    for(int i=0;i<SKN;i++) bvals[i] = W[(size_t)(k0+sk0+i)*N + sc];

    __syncthreads();

    *(f16x8*)&Ah[sar*AST + sak]     = av[0];
    *(f16x8*)&Ah[sar*AST + sak + 8] = av[1];
    #pragma unroll
    for(int s=0;s<SKN/8;s++){
      f16x8 hi, lo;
      #pragma unroll
      for(int j=0;j<8;j++){
        float x = bvals[s*8+j];
        f16 h = (f16)x;
        hi[j] = h; lo[j] = (f16)(x - (float)h);
      }
      *(f16x8*)&Bh[sc*AST + sk0 + s*8] = hi;
      *(f16x8*)&Bl[sc*AST + sk0 + s*8] = lo;
    }
    __syncthreads();

    f16x8 af[NM], bfh[NN], bfl[NN];
    #pragma unroll
    for(int m=0;m<NM;m++){
      int r = wr*64 + m*16 + lr;
      af[m] = *(const f16x8*)&Ah[r*AST + lk*8];
    }
    #pragma unroll
    for(int n=0;n<NN;n++){
      int c = wc*(BN/2) + n*16 + lr;
      bfh[n] = *(const f16x8*)&Bh[c*AST + lk*8];
      bfl[n] = *(const f16x8*)&Bl[c*AST + lk*8];
    }
    #pragma unroll
    for(int m=0;m<NM;m++)
      #pragma unroll
      for(int n=0;n<NN;n++){
        acc[m][n] = __builtin_amdgcn_mfma_f32_16x16x32_f16(af[m], bfh[n], acc[m][n], 0,0,0);
        acc[m][n] = __builtin_amdgcn_mfma_f32_16x16x32_f16(af[m], bfl[n], acc[m][n], 0,0,0);
      }
  }

  #pragma unroll
  for(int m=0;m<NM;m++){
    int grb = row0 + wr*64 + m*16 + lk*4;
    #pragma unroll
    for(int reg=0;reg<4;reg++){
      int gr = grb + reg;
      if(gr < M){
        float dv = dinv[gr];
        #pragma unroll
        for(int n=0;n<NN;n++){
          int gc = wc*(BN/2) + n*16 + lr;
          Hh[(size_t)gr*N + gc] = (f16)(acc[m][n][reg] * dv);
        }
      }
    }
  }
}

// gather layer1: wave per node; 16 lanes x f16x8 cover the 128-col row; each
// wave-instruction fetches FOUR edges' rows. Per-edge fma with dinv[src].
__global__ void k_gather_l1(const int* __restrict__ off, const int* __restrict__ ssrc,
                            const f16* __restrict__ g, const float* __restrict__ dinv,
                            const float* __restrict__ bias, f16* __restrict__ outh, int M){
  const int w = (blockIdx.x*blockDim.x + threadIdx.x) >> 6;
  const int l = threadIdx.x & 63;
  if(w >= M) return;
  const int q = l>>4, c = l&15;
  const f16x8* g8 = (const f16x8*)g;        // row stride = 16 f16x8
  float acc[8] = {0.f,0.f,0.f,0.f,0.f,0.f,0.f,0.f};
  const int e0 = off[w], e1 = off[w+1];
  const int ne = e1 - e0;
  int i = e0 + q;
  for(int it = ne>>2; it>0; --it, i+=4){
    int s = ssrc[i];
    float ds = dinv[s];
    f16x8 v = g8[(size_t)s*16 + c];
    #pragma unroll
    for(int j=0;j<8;j++) acc[j] = fmaf((float)v[j], ds, acc[j]);
  }
  if(q < (ne & 3)){
    int s = ssrc[i];
    float ds = dinv[s];
    f16x8 v = g8[(size_t)s*16 + c];
    #pragma unroll
    for(int j=0;j<8;j++) acc[j] = fmaf((float)v[j], ds, acc[j]);
  }
  const float dw = dinv[w];
  if(q == 0){                                // self-loop term
    f16x8 v = g8[(size_t)w*16 + c];
    #pragma unroll
    for(int j=0;j<8;j++) acc[j] = fmaf((float)v[j], dw, acc[j]);
  }
  #pragma unroll
  for(int j=0;j<8;j++){
    acc[j] += __shfl_xor(acc[j], 16);
    acc[j] += __shfl_xor(acc[j], 32);
  }
  if(q == 0){
    float4 b0 = ((const float4*)bias)[c*2];
    float4 b1 = ((const float4*)bias)[c*2+1];
    f16x8 o;
    o[0] = (f16)fmaxf(fmaf(acc[0], dw, b0.x), 0.f);
    o[1] = (f16)fmaxf(fmaf(acc[1], dw, b0.y), 0.f);
    o[2] = (f16)fmaxf(fmaf(acc[2], dw, b0.z), 0.f);
    o[3] = (f16)fmaxf(fmaf(acc[3], dw, b0.w), 0.f);
    o[4] = (f16)fmaxf(fmaf(acc[4], dw, b1.x), 0.f);
    o[5] = (f16)fmaxf(fmaf(acc[5], dw, b1.y), 0.f);
    o[6] = (f16)fmaxf(fmaf(acc[6], dw, b1.z), 0.f);
    o[7] = (f16)fmaxf(fmaf(acc[7], dw, b1.w), 0.f);
    ((f16x8*)outh)[(size_t)w*16 + c] = o;
  }
}

// gather layer2: wave per node; 8 lanes x f16x8 cover the 64-col row -> EIGHT
// edges per wave-instruction. g (h2h) is pre-scaled by dinv[src]; f32 output.
__global__ void k_gather_l2(const int* __restrict__ off, const int* __restrict__ ssrc,
                            const f16* __restrict__ g, const float* __restrict__ dinv,
                            const float* __restrict__ bias, float* __restrict__ out, int M){
  const int w = (blockIdx.x*blockDim.x + threadIdx.x) >> 6;
  const int l = threadIdx.x & 63;
  if(w >= M) return;
  const int grp = l>>3, c = l&7;
  const f16x8* g8 = (const f16x8*)g;        // row stride = 8 f16x8
  float acc[8] = {0.f,0.f,0.f,0.f,0.f,0.f,0.f,0.f};
  const int e0 = off[w], e1 = off[w+1];
  const int ne = e1 - e0;
  int i = e0 + grp;
  for(int it = ne>>3; it>0; --it, i+=8){
    int s = ssrc[i];
    f16x8 v = g8[(size_t)s*8 + c];
    #pragma unroll
    for(int j=0;j<8;j++) acc[j] += (float)v[j];
  }
  if(grp < (ne & 7)){
    int s = ssrc[i];
    f16x8 v = g8[(size_t)s*8 + c];
    #pragma unroll
    for(int j=0;j<8;j++) acc[j] += (float)v[j];
  }
  if(grp == 0){                              // self-loop (already *dinv[w])
    f16x8 v = g8[(size_t)w*8 + c];
    #pragma unroll
    for(int j=0;j<8;j++) acc[j] += (float)v[j];
  }
  #pragma unroll
  for(int j=0;j<8;j++){
    acc[j] += __shfl_xor(acc[j], 8);
    acc[j] += __shfl_xor(acc[j], 16);
    acc[j] += __shfl_xor(acc[j], 32);
  }
  if(grp == 0){
    const float dw = dinv[w];
    float4 b0 = ((const float4*)bias)[c*2];
    float4 b1 = ((const float4*)bias)[c*2+1];
    float4 o0, o1;
    o0.x = fmaf(acc[0], dw, b0.x);
    o0.y = fmaf(acc[1], dw, b0.y);
    o0.z = fmaf(acc[2], dw, b0.z);
    o0.w = fmaf(acc[3], dw, b0.w);
    o1.x = fmaf(acc[4], dw, b1.x);
    o1.y = fmaf(acc[5], dw, b1.y);
    o1.z = fmaf(acc[6], dw, b1.z);
    o1.w = fmaf(acc[7], dw, b1.w);
    ((float4*)out)[(size_t)w*16 + c*2]     = o0;
    ((float4*)out)[(size_t)w*16 + c*2 + 1] = o1;
  }
}

extern "C" void kernel_launch(void* const* d_in, const int* in_sizes, int n_in,
                              void* d_out, int out_size, void* d_ws, size_t ws_size,
                              hipStream_t stream){
  const float* feat = (const float*)d_in[0];
  const int*   ei   = (const int*)d_in[1];
  const float* W1   = (const float*)d_in[2];
  const float* b1   = (const float*)d_in[3];
  const float* W2   = (const float*)d_in[4];
  const float* b2   = (const float*)d_in[5];
  float* out = (float*)d_out;

  const int M = in_sizes[0] / 256;   // 50000 nodes
  const int E = in_sizes[1] / 2;     // 800000 edges

  float* ws = (float*)d_ws;
  unsigned* cnt  = (unsigned*)ws;             // [0, 50176)
  float*    dinv = ws + 50176;                // [50176, 100352)
  int*      off  = (int*)(ws + 100352);       // 50001 ints
  int*      curs = (int*)(ws + 150656);       // 50176 ints
  int*      part = (int*)(ws + 200832);       // 64 ints
  int*      ssrc = (int*)(ws + 200960);       // 800000 ints
  f16*      h1h  = (f16*)(ws + 1000960);      // M*128 f16
  f16*      o1h  = (f16*)(ws + 4200960);      // M*128 f16
  f16*      h2h  = h1h;                       // reuse (dead after gather1)

  const int nbN = (M + THREADS-1)/THREADS;
  const int nbE = (E + THREADS-1)/THREADS;
  const int nbScan = (M + 1023)/1024;         // 49
  const int gemmBlocks = (M + 127)/128;       // 391
  const int CNT_BLOCKS = 2048;

  hipMemsetAsync(cnt, 0, (size_t)M*sizeof(unsigned), stream);

  // fused: layer-1 GEMM (MFMA-bound) overlapped with XCD-partitioned degree count
  k_gemm1_count<256,128><<<gemmBlocks + CNT_BLOCKS, THREADS, 0, stream>>>(
      feat, W1, h1h, M, ei + E, cnt, E, gemmBlocks, CNT_BLOCKS);

  k_scan_local<<<nbScan, 256, 0, stream>>>(cnt, off, part, M);
  k_scan_add<<<nbN, THREADS, 0, stream>>>(cnt, off, part, dinv, curs, M, E, nbScan);
  k_build<<<nbE*8, THREADS, 0, stream>>>(ei, curs, ssrc, E, M);

  k_gather_l1<<<(M*64 + THREADS-1)/THREADS, THREADS, 0, stream>>>(off, ssrc, h1h, dinv, b1, o1h, M);

  k_gemm_mfma_f16a<128,64><<<gemmBlocks, THREADS, 0, stream>>>(o1h, W2, dinv, h2h, M);
  k_gather_l2<<<(M*64 + THREADS-1)/THREADS, THREADS, 0, stream>>>(off, ssrc, h2h, dinv, b2, out, M);
}